// Round 10
// baseline (169.910 us; speedup 1.0000x reference)
//
#include <hip/hip_runtime.h>
#include <hip/hip_bf16.h>

typedef __bf16 bf16x8 __attribute__((ext_vector_type(8)));
typedef __bf16 bf16x4 __attribute__((ext_vector_type(4)));
typedef float  f32x4  __attribute__((ext_vector_type(4)));

#define T_SEQ 2048
#define D_HEAD 64
#define BH_N 32
#define NT_TILES (T_SEQ / 64)        // 32
#define QT_N 32                      // 64 q-rows per block
#define IMG_BYTES 16384              // per-(bh,kt) tile image: 8KB K + 8KB V
#define SCALE_LOG2 0.18033688011112042f   // 0.125 * log2(e)

#define WS_IMG ((size_t)0)
#define WS_MB  ((size_t)16u << 20)

static __device__ __forceinline__ f32x4 mfma32(bf16x8 a, bf16x8 b, f32x4 c) {
    return __builtin_amdgcn_mfma_f32_16x16x32_bf16(a, b, c, 0, 0, 0);
}

static __device__ __forceinline__ float fast_exp2(float x) {
#if __has_builtin(__builtin_amdgcn_exp2f)
    return __builtin_amdgcn_exp2f(x);   // raw v_exp_f32; inputs bounded, no fixup needed
#else
    return exp2f(x);
#endif
}

static __device__ __forceinline__ int sext_bit(unsigned w, int idx) {
#if __has_builtin(__builtin_amdgcn_sbfe)
    return __builtin_amdgcn_sbfe((int)w, idx, 1);      // v_bfe_i32: 1 instr
#else
    return (int)(w << (31 - idx)) >> 31;
#endif
}

// async global->LDS, 16B per lane. LDS dest is wave-uniform base + lane*16 (HW rule);
// the swizzle lives in the GLOBAL image layout, LDS stays linear.
static __device__ __forceinline__ void gload16(const void* g, void* l, int lane) {
#if __has_builtin(__builtin_amdgcn_global_load_lds)
    (void)lane;
    __builtin_amdgcn_global_load_lds(
        (const __attribute__((address_space(1))) void*)g,
        (__attribute__((address_space(3))) void*)l, 16, 0, 0);
#else
    *((f32x4*)l + lane) = *(const f32x4*)g;
#endif
}

// ---------------- prepass: build per-tile LDS images ----------------
// Image for (bh,kt), 16KB:
//   K half (8KB): row kr (key 0..63) x 128B; 16B chunk m = K[key][d-chunk m^(kr&7)]
//   V half (8KB): row r  (d   0..63) x 128B; 16B chunk m: u=m^(r&7), kh=u&1, g=u>>1,
//       bytes0-7 = V[32kh+4g+{0..3}][d=r], bytes8-15 = V[32kh+16+4g+{0..3}][d=r]

__global__ __launch_bounds__(256) void prep_kv(const float* __restrict__ k,
                                               const float* __restrict__ v,
                                               char* __restrict__ img) {
    __shared__ __bf16 t[64][72];
    const int bh = blockIdx.y, tt = blockIdx.x, tid = threadIdx.x;
    char* ob = img + ((size_t)bh * NT_TILES + tt) * IMG_BYTES;
    {
        const int kr = tid >> 2, qd = tid & 3, ke = kr & 7;
        const size_t base = ((size_t)bh * T_SEQ + tt * 64 + kr) * D_HEAD + qd * 16;
        const float4 a0 = *(const float4*)(k + base);
        const float4 a1 = *(const float4*)(k + base + 4);
        const float4 a2 = *(const float4*)(k + base + 8);
        const float4 a3 = *(const float4*)(k + base + 12);
        bf16x8 w0, w1;
        w0[0]=(__bf16)a0.x; w0[1]=(__bf16)a0.y; w0[2]=(__bf16)a0.z; w0[3]=(__bf16)a0.w;
        w0[4]=(__bf16)a1.x; w0[5]=(__bf16)a1.y; w0[6]=(__bf16)a1.z; w0[7]=(__bf16)a1.w;
        w1[0]=(__bf16)a2.x; w1[1]=(__bf16)a2.y; w1[2]=(__bf16)a2.z; w1[3]=(__bf16)a2.w;
        w1[4]=(__bf16)a3.x; w1[5]=(__bf16)a3.y; w1[6]=(__bf16)a3.z; w1[7]=(__bf16)a3.w;
        *(bf16x8*)(ob + kr * 128 + (((2 * qd + 0) ^ ke) << 4)) = w0;
        *(bf16x8*)(ob + kr * 128 + (((2 * qd + 1) ^ ke) << 4)) = w1;
    }
    {
        const int tr = tid >> 4, c4 = (tid & 15) * 4;
        const float* src = v + ((size_t)bh * T_SEQ + tt * 64) * D_HEAD;
#pragma unroll
        for (int p = 0; p < 4; ++p) {
            const int row = p * 16 + tr;
            const float4 f = *(const float4*)(src + row * D_HEAD + c4);
            t[c4+0][row] = (__bf16)f.x; t[c4+1][row] = (__bf16)f.y;
            t[c4+2][row] = (__bf16)f.z; t[c4+3][row] = (__bf16)f.w;
        }
        __syncthreads();
        const int d = tid >> 2;
        char* vb = ob + 8192 + d * 128;
#pragma unroll
        for (int mi = 0; mi < 2; ++mi) {
            const int m  = (tid & 3) * 2 + mi;
            const int u  = m ^ (d & 7);
            const int k0 = (u & 1) * 32 + (u >> 1) * 4;
            const bf16x4 lo = *(const bf16x4*)&t[d][k0];
            const bf16x4 hi = *(const bf16x4*)&t[d][k0 + 16];
            *(bf16x8*)(vb + m * 16) = __builtin_shufflevector(lo, hi, 0,1,2,3,4,5,6,7);
        }
    }
}

// mask prepass: transposed + pre-inverted + kh-pre-split keep-bit words.
// nbt[(t*2 + kh)*2048 + row] = ~bits(mask[row][t*64 + kh*32 .. +31])
__global__ void mpack(const int* __restrict__ m, unsigned* __restrict__ nbt) {
    const int i = blockIdx.x * 256 + threadIdx.x;
    const unsigned long long b = __ballot(m[i] != 0);
    if ((threadIdx.x & 63) == 0) {
        const int wi  = i >> 6;          // word index = row*32 + t
        const int row = wi >> 5;
        const int t   = wi & 31;
        nbt[(size_t)(t * 2 + 0) * 2048 + row] = ~(unsigned)b;
        nbt[(size_t)(t * 2 + 1) * 2048 + row] = ~(unsigned)(b >> 32);
    }
}

// ---------------- main kernel ----------------
// attn17 = attn12's high-occupancy geometry REVALIDATED with the R8/R9 micro-fixes.
// QTILE=64, 512 thr, 8 waves (qp=w&3 -> 16-q group, kh=w>>2 -> 32-key half), grid 1024
// -> 4 blocks/CU (LDS 4x33,280=133K, threads 4x512=2048=CU max) = 8 waves/SIMD from 4
// INDEPENDENT 8-wave barrier domains. attn12's regression vs attn11 is quantitatively
// explained by its strided mask gathers (1024 L2 lines/CU-tile), not an L2-BW ceiling
// (true L2 ~34 TB/s >> the 7.1 observed); those gathers are now the coalesced nbt path
// (1 u32/wave-tile, ~64 lines/CU-tile). Also: z4 C-init, sbfe keep-bit, hoisted
// offsets, static 2-tile unroll, setprio. attn12 measured 32 VGPR -> launch_bounds(512,8).

__global__ __launch_bounds__(512, 8) void attn17(
    const float* __restrict__ q, const char* __restrict__ img,
    const unsigned* __restrict__ nbt, float* __restrict__ out)
{
    // XCD swizzle: XCD x hosts bh in [4x,4x+4), all qt. Bijective over 1024 blocks.
    const int l   = blockIdx.x;          // 0..1023
    const int bh  = ((l & 7) << 2) | ((l >> 3) & 3);
    const int qt  = l >> 5;              // 0..31 (64 q rows each)

    const int tid = threadIdx.x, wave = tid >> 6, lane = tid & 63;
    const int g = lane >> 4, ln = lane & 15;
    const int qp = wave & 3, kh = wave >> 2;
    const int g4 = g * 4;

    __shared__ __align__(16) char smem[33280];
    float* Ep = (float*)smem;                // epilogue overlay: [2][64][64] f32
    float* Os = (float*)(smem + 32768);      // row sums [2][64]

    const int qw = qt * 64 + qp * 16;

    // ---- Q B-frags (log2-scaled): lane holds Q[qw+ln][kc*32+g*8+j]
    bf16x8 qf[2];
    {
        const float* qpt = q + ((size_t)bh * T_SEQ + qw + ln) * D_HEAD + g * 8;
#pragma unroll
        for (int kc = 0; kc < 2; ++kc) {
            const float4 f0 = *(const float4*)(qpt + kc * 32);
            const float4 f1 = *(const float4*)(qpt + kc * 32 + 4);
            qf[kc][0]=(__bf16)(f0.x*SCALE_LOG2); qf[kc][1]=(__bf16)(f0.y*SCALE_LOG2);
            qf[kc][2]=(__bf16)(f0.z*SCALE_LOG2); qf[kc][3]=(__bf16)(f0.w*SCALE_LOG2);
            qf[kc][4]=(__bf16)(f1.x*SCALE_LOG2); qf[kc][5]=(__bf16)(f1.y*SCALE_LOG2);
            qf[kc][6]=(__bf16)(f1.z*SCALE_LOG2); qf[kc][7]=(__bf16)(f1.w*SCALE_LOG2);
        }
    }

    f32x4 o[4];
#pragma unroll
    for (int mt = 0; mt < 4; ++mt) o[mt] = (f32x4){0.f, 0.f, 0.f, 0.f};
    f32x4 osum = (f32x4){0.f, 0.f, 0.f, 0.f};
    const bf16x8 ones8 = { (__bf16)1.0f, (__bf16)1.0f, (__bf16)1.0f, (__bf16)1.0f,
                           (__bf16)1.0f, (__bf16)1.0f, (__bf16)1.0f, (__bf16)1.0f };
    const f32x4 z4 = (f32x4){0.f, 0.f, 0.f, 0.f};   // persistent MFMA C-init

    const char* ibase = img + (size_t)bh * (NT_TILES * (size_t)IMG_BYTES);
    // pre-split by kh, pre-inverted; per tile advance = uniform 4096 elements
    const unsigned* nb_base = nbt + (size_t)kh * 2048 + qw;

    // ---- loop-invariant LDS read offsets (hoisted once)
    int koffs[2][2];
#pragma unroll
    for (int ntl = 0; ntl < 2; ++ntl) {
        const int row = (2 * kh + ntl) * 16 + ln;
        const int rb = row * 128 + ((g ^ (ln & 7)) << 4);
        koffs[ntl][0] = rb; koffs[ntl][1] = rb ^ 64;
    }
    int voffs[4];
#pragma unroll
    for (int mt = 0; mt < 4; ++mt)
        voffs[mt] = (mt * 16 + ln) * 128 + ((((g << 1) | kh) ^ (ln & 7)) << 4);

    char* buf0 = smem;
    char* buf1 = smem + 16384;

    auto stage = [&](int tile, char* dstbase) {
        const char* src = ibase + (size_t)tile * IMG_BYTES + wave * 2048 + lane * 16;
        char* dst = dstbase + wave * 2048;
        gload16(src, dst, lane);
        gload16(src + 1024, dst + 1024, lane);
    };

    auto compute_tile = [&](const char* KB, unsigned nw) {
        const char* VB = KB + 8192;
        const unsigned nbs = nw >> g4;   // pre-inverted keep word, this wave's kh half

        // batch the 4 K b128 reads up front
        bf16x8 ka[2][2];
#pragma unroll
        for (int ntl = 0; ntl < 2; ++ntl) {
            ka[ntl][0] = *(const bf16x8*)(KB + koffs[ntl][0]);
            ka[ntl][1] = *(const bf16x8*)(KB + koffs[ntl][1]);
        }

        // ---- S^T = K.Q^T; exp2 + mask -> merged P frag (key perm: j<4 grp0, j>=4 grp1)
        bf16x8 pa8;
#pragma unroll
        for (int ntl = 0; ntl < 2; ++ntl) {
            __builtin_amdgcn_s_setprio(1);
            f32x4 c = mfma32(ka[ntl][0], qf[0], z4);
            c = mfma32(ka[ntl][1], qf[1], c);
            __builtin_amdgcn_s_setprio(0);
#pragma unroll
            for (int r = 0; r < 4; ++r) {
                const float e = fast_exp2(c[r]);
                const int keep = sext_bit(nbs, ntl * 16 + r);
                const float p = __builtin_bit_cast(float,
                    __builtin_bit_cast(unsigned, e) & (unsigned)keep);
                pa8[ntl * 4 + r] = (__bf16)p;
            }
        }

        // ---- row-sum + PV (B-frag vv covers both key groups per b128 read)
        bf16x8 vv[4];
#pragma unroll
        for (int mt = 0; mt < 4; ++mt) vv[mt] = *(const bf16x8*)(VB + voffs[mt]);
        __builtin_amdgcn_s_setprio(1);
        osum = mfma32(pa8, ones8, osum);
#pragma unroll
        for (int mt = 0; mt < 4; ++mt)
            o[mt] = mfma32(pa8, vv[mt], o[mt]);
        __builtin_amdgcn_s_setprio(0);
    };

    // prologue: tile 0 -> buf0 (8 waves x 2KB each)
    stage(0, buf0);
    unsigned mwA = nb_base[ln];
    __syncthreads();

#pragma unroll 1
    for (int i = 0; i < NT_TILES / 2; ++i) {
        const int t = 2 * i;
        // half A: consume buf0 (tile t), prefetch tile t+1 -> buf1
        stage(t + 1, buf1);
        const unsigned mwB = nb_base[(size_t)(t + 1) * 4096 + ln];
        compute_tile(buf0, mwA);
        __syncthreads();
        // half B: consume buf1 (tile t+1), prefetch tile t+2 -> buf0
        if (i < NT_TILES / 2 - 1) {
            stage(t + 2, buf0);
            mwA = nb_base[(size_t)(t + 2) * 4096 + ln];
        }
        compute_tile(buf1, mwB);
        __syncthreads();
    }

    // ---- epilogue: single pass, all 8 waves write distinct (kh, qp) regions
#pragma unroll
    for (int mt = 0; mt < 4; ++mt)
#pragma unroll
        for (int r = 0; r < 4; ++r)
            Ep[(size_t)kh * 4096 + (qp * 16 + g * 4 + r) * 64 + mt * 16 + ln] = o[mt][r];
    if (ln == 0) {
#pragma unroll
        for (int r = 0; r < 4; ++r)
            Os[kh * 64 + qp * 16 + g * 4 + r] = osum[r];
    }
    __syncthreads();
    // cooperative, coalesced output: 64 rows x 64 d fp32 (512 threads -> 2 quads each)
#pragma unroll
    for (int p2 = 0; p2 < 2; ++p2) {
        const int idx = p2 * 512 + tid;
        const int row = idx >> 4, c4 = (idx & 15) * 4;
        const float sl = Os[row] + Os[64 + row];
        const float inv = (sl > 0.f) ? (1.f / sl) : 0.f;
        const float4 a  = *(const float4*)(Ep + row * 64 + c4);
        const float4 b4 = *(const float4*)(Ep + 4096 + row * 64 + c4);
        const float4 st = { (a.x + b4.x) * inv, (a.y + b4.y) * inv,
                            (a.z + b4.z) * inv, (a.w + b4.w) * inv };
        *(float4*)(out + ((size_t)bh * T_SEQ + qt * 64 + row) * D_HEAD + c4) = st;
    }
}

extern "C" void kernel_launch(void* const* d_in, const int* in_sizes, int n_in,
                              void* d_out, int out_size, void* d_ws, size_t ws_size,
                              hipStream_t stream) {
    const float* q    = (const float*)d_in[0];
    const float* k    = (const float*)d_in[1];
    const float* v    = (const float*)d_in[2];
    const int*   mask = (const int*)d_in[3];
    float*       out  = (float*)d_out;

    char* img = (char*)d_ws + WS_IMG;
    unsigned* nbt = (unsigned*)((char*)d_ws + WS_MB);

    prep_kv<<<dim3(NT_TILES, BH_N), 256, 0, stream>>>(k, v, img);
    mpack<<<(T_SEQ * T_SEQ) / 256, 256, 0, stream>>>(mask, nbt);
    attn17<<<dim3(QT_N * BH_N), 512, 0, stream>>>(q, img, nbt, out);
}

// Round 11
// 163.294 us; speedup vs baseline: 1.0405x; 1.0405x over previous
//
#include <hip/hip_runtime.h>
#include <hip/hip_bf16.h>

typedef __bf16 bf16x8 __attribute__((ext_vector_type(8)));
typedef __bf16 bf16x4 __attribute__((ext_vector_type(4)));
typedef float  f32x4  __attribute__((ext_vector_type(4)));

#define T_SEQ 2048
#define D_HEAD 64
#define BH_N 32
#define NT_TILES (T_SEQ / 64)        // 32
#define QT_N 8                       // 256 q-rows per block
#define IMG_BYTES 16384              // per-(bh,kt) tile image: 8KB K + 8KB V
#define SCALE_LOG2 0.18033688011112042f   // 0.125 * log2(e)

#define WS_IMG ((size_t)0)
#define WS_MB  ((size_t)16u << 20)

static __device__ __forceinline__ f32x4 mfma32(bf16x8 a, bf16x8 b, f32x4 c) {
    return __builtin_amdgcn_mfma_f32_16x16x32_bf16(a, b, c, 0, 0, 0);
}

static __device__ __forceinline__ float fast_exp2(float x) {
#if __has_builtin(__builtin_amdgcn_exp2f)
    return __builtin_amdgcn_exp2f(x);   // raw v_exp_f32; inputs bounded, no fixup needed
#else
    return exp2f(x);
#endif
}

static __device__ __forceinline__ int sext_bit(unsigned w, int idx) {
#if __has_builtin(__builtin_amdgcn_sbfe)
    return __builtin_amdgcn_sbfe((int)w, idx, 1);      // v_bfe_i32: 1 instr
#else
    return (int)(w << (31 - idx)) >> 31;
#endif
}

// async global->LDS, 16B per lane. LDS dest is wave-uniform base + lane*16 (HW rule);
// the swizzle lives in the GLOBAL image layout, LDS stays linear.
static __device__ __forceinline__ void gload16(const void* g, void* l, int lane) {
#if __has_builtin(__builtin_amdgcn_global_load_lds)
    (void)lane;
    __builtin_amdgcn_global_load_lds(
        (const __attribute__((address_space(1))) void*)g,
        (__attribute__((address_space(3))) void*)l, 16, 0, 0);
#else
    *((f32x4*)l + lane) = *(const f32x4*)g;
#endif
}

// ---------------- prepass: build per-tile LDS images ----------------
// Image for (bh,kt), 16KB:
//   K half (8KB): row kr (key 0..63) x 128B; 16B chunk m = K[key][d-chunk m^(kr&7)]
//   V half (8KB): row r  (d   0..63) x 128B; 16B chunk m: u=m^(r&7), kh=u&1, g=u>>1,
//       bytes0-7 = V[32kh+4g+{0..3}][d=r], bytes8-15 = V[32kh+16+4g+{0..3}][d=r]

__global__ __launch_bounds__(256) void prep_kv(const float* __restrict__ k,
                                               const float* __restrict__ v,
                                               char* __restrict__ img) {
    __shared__ __bf16 t[64][72];
    const int bh = blockIdx.y, tt = blockIdx.x, tid = threadIdx.x;
    char* ob = img + ((size_t)bh * NT_TILES + tt) * IMG_BYTES;
    {
        const int kr = tid >> 2, qd = tid & 3, ke = kr & 7;
        const size_t base = ((size_t)bh * T_SEQ + tt * 64 + kr) * D_HEAD + qd * 16;
        const float4 a0 = *(const float4*)(k + base);
        const float4 a1 = *(const float4*)(k + base + 4);
        const float4 a2 = *(const float4*)(k + base + 8);
        const float4 a3 = *(const float4*)(k + base + 12);
        bf16x8 w0, w1;
        w0[0]=(__bf16)a0.x; w0[1]=(__bf16)a0.y; w0[2]=(__bf16)a0.z; w0[3]=(__bf16)a0.w;
        w0[4]=(__bf16)a1.x; w0[5]=(__bf16)a1.y; w0[6]=(__bf16)a1.z; w0[7]=(__bf16)a1.w;
        w1[0]=(__bf16)a2.x; w1[1]=(__bf16)a2.y; w1[2]=(__bf16)a2.z; w1[3]=(__bf16)a2.w;
        w1[4]=(__bf16)a3.x; w1[5]=(__bf16)a3.y; w1[6]=(__bf16)a3.z; w1[7]=(__bf16)a3.w;
        *(bf16x8*)(ob + kr * 128 + (((2 * qd + 0) ^ ke) << 4)) = w0;
        *(bf16x8*)(ob + kr * 128 + (((2 * qd + 1) ^ ke) << 4)) = w1;
    }
    {
        const int tr = tid >> 4, c4 = (tid & 15) * 4;
        const float* src = v + ((size_t)bh * T_SEQ + tt * 64) * D_HEAD;
#pragma unroll
        for (int p = 0; p < 4; ++p) {
            const int row = p * 16 + tr;
            const float4 f = *(const float4*)(src + row * D_HEAD + c4);
            t[c4+0][row] = (__bf16)f.x; t[c4+1][row] = (__bf16)f.y;
            t[c4+2][row] = (__bf16)f.z; t[c4+3][row] = (__bf16)f.w;
        }
        __syncthreads();
        const int d = tid >> 2;
        char* vb = ob + 8192 + d * 128;
#pragma unroll
        for (int mi = 0; mi < 2; ++mi) {
            const int m  = (tid & 3) * 2 + mi;
            const int u  = m ^ (d & 7);
            const int k0 = (u & 1) * 32 + (u >> 1) * 4;
            const bf16x4 lo = *(const bf16x4*)&t[d][k0];
            const bf16x4 hi = *(const bf16x4*)&t[d][k0 + 16];
            *(bf16x8*)(vb + m * 16) = __builtin_shufflevector(lo, hi, 0,1,2,3,4,5,6,7);
        }
    }
}

// mask prepass: transposed + pre-inverted + kh-pre-split keep-bit words.
// nbt[(t*2 + kh)*2048 + row] = ~bits(mask[row][t*64 + kh*32 .. +31])
__global__ void mpack(const int* __restrict__ m, unsigned* __restrict__ nbt) {
    const int i = blockIdx.x * 256 + threadIdx.x;
    const unsigned long long b = __ballot(m[i] != 0);
    if ((threadIdx.x & 63) == 0) {
        const int wi  = i >> 6;          // word index = row*32 + t
        const int row = wi >> 5;
        const int t   = wi & 31;
        nbt[(size_t)(t * 2 + 0) * 2048 + row] = ~(unsigned)b;
        nbt[(size_t)(t * 2 + 1) * 2048 + row] = ~(unsigned)(b >> 32);
    }
}

// ---------------- main kernel ----------------
// attn18: QTILE=256 (the traffic-minimizing end of the measured traffic<->dur scaling:
// 128MB image traffic = 2.5 TB/s, half of attn16's). Grid 256 = exactly 1 block/CU,
// 512 thr = 8 waves, wave = (qp=w&3 -> 64-q group, kh=w>>2 -> 32-key half). Each wave
// carries FOUR independent q-subtile chains (qs=0..3: QK->exp->pack) -> per-wave ILP
// replaces the TLP that R5/R7 proved useless; LDS-reads/q and mask/loop overhead/q are
// halved/quartered vs attn16 (ka+vv shared across qs). 1 block/CU frees LDS: 8x16KB
// buffer ring + barrier every 2 tiles (16 barriers), stage-ahead 6 tiles so every
// barrier drain sees loads issued a full window earlier. Fragment math / image layout /
// mask path byte-identical to verified attn16, qs extended 2->4 with static unrolls.

__global__ __launch_bounds__(512, 2) void attn18(
    const float* __restrict__ q, const char* __restrict__ img,
    const unsigned* __restrict__ nbt, float* __restrict__ out)
{
    // XCD swizzle over 256 blocks: XCD x hosts bh in [4x,4x+4), all qt. Bijective.
    const int l   = blockIdx.x;          // 0..255
    const int bh  = ((l & 7) << 2) | ((l >> 3) & 3);
    const int qt  = l >> 5;              // 0..7 (256 q rows each)

    const int tid = threadIdx.x, wave = tid >> 6, lane = tid & 63;
    const int g = lane >> 4, ln = lane & 15;
    const int qp = wave & 3, kh = wave >> 2;
    const int g4 = g * 4;

    __shared__ __align__(16) char smem[133120];   // 8x16KB ring + 2KB Os
    float* Ep = (float*)smem;                 // epilogue overlay: [2][128][64] f32 (b0..b3)
    float* Os = (float*)(smem + 131072);      // row sums [2][128] per pass

    const int qw = qt * 256 + qp * 64;

    // ---- Q B-frags (log2-scaled): lane holds Q[qw+qs*16+ln][kc*32+g*8+j]
    bf16x8 qf[4][2];
#pragma unroll
    for (int qs = 0; qs < 4; ++qs) {
        const float* qpt = q + ((size_t)bh * T_SEQ + qw + qs * 16 + ln) * D_HEAD + g * 8;
#pragma unroll
        for (int kc = 0; kc < 2; ++kc) {
            const float4 f0 = *(const float4*)(qpt + kc * 32);
            const float4 f1 = *(const float4*)(qpt + kc * 32 + 4);
            qf[qs][kc][0]=(__bf16)(f0.x*SCALE_LOG2); qf[qs][kc][1]=(__bf16)(f0.y*SCALE_LOG2);
            qf[qs][kc][2]=(__bf16)(f0.z*SCALE_LOG2); qf[qs][kc][3]=(__bf16)(f0.w*SCALE_LOG2);
            qf[qs][kc][4]=(__bf16)(f1.x*SCALE_LOG2); qf[qs][kc][5]=(__bf16)(f1.y*SCALE_LOG2);
            qf[qs][kc][6]=(__bf16)(f1.z*SCALE_LOG2); qf[qs][kc][7]=(__bf16)(f1.w*SCALE_LOG2);
        }
    }

    f32x4 o[4][4];
#pragma unroll
    for (int qs = 0; qs < 4; ++qs)
#pragma unroll
        for (int mt = 0; mt < 4; ++mt) o[qs][mt] = (f32x4){0.f, 0.f, 0.f, 0.f};
    f32x4 osum[4] = { (f32x4){0.f,0.f,0.f,0.f}, (f32x4){0.f,0.f,0.f,0.f},
                      (f32x4){0.f,0.f,0.f,0.f}, (f32x4){0.f,0.f,0.f,0.f} };
    const bf16x8 ones8 = { (__bf16)1.0f, (__bf16)1.0f, (__bf16)1.0f, (__bf16)1.0f,
                           (__bf16)1.0f, (__bf16)1.0f, (__bf16)1.0f, (__bf16)1.0f };
    const f32x4 z4 = (f32x4){0.f, 0.f, 0.f, 0.f};   // persistent MFMA C-init

    const char* ibase = img + (size_t)bh * (NT_TILES * (size_t)IMG_BYTES);
    const unsigned* nb_base = nbt + (size_t)kh * 2048 + qw;

    // ---- loop-invariant LDS read offsets (hoisted once)
    int koffs[2][2];
#pragma unroll
    for (int ntl = 0; ntl < 2; ++ntl) {
        const int row = (2 * kh + ntl) * 16 + ln;
        const int rb = row * 128 + ((g ^ (ln & 7)) << 4);
        koffs[ntl][0] = rb; koffs[ntl][1] = rb ^ 64;
    }
    int voffs[4];
#pragma unroll
    for (int mt = 0; mt < 4; ++mt)
        voffs[mt] = (mt * 16 + ln) * 128 + ((((g << 1) | kh) ^ (ln & 7)) << 4);

    char* const b0 = smem;              char* const b1 = smem + 16384;
    char* const b2 = smem + 32768;      char* const b3 = smem + 49152;
    char* const b4 = smem + 65536;      char* const b5 = smem + 81920;
    char* const b6 = smem + 98304;      char* const b7 = smem + 114688;

    auto stage = [&](int tile, char* dstbase) {
        const char* src = ibase + (size_t)tile * IMG_BYTES + wave * 2048 + lane * 16;
        char* dst = dstbase + wave * 2048;
        gload16(src, dst, lane);
        gload16(src + 1024, dst + 1024, lane);
    };

    auto compute_tile = [&](const char* KB, const unsigned* nw) {
        const char* VB = KB + 8192;
        unsigned nbs[4];
#pragma unroll
        for (int qs = 0; qs < 4; ++qs) nbs[qs] = nw[qs] >> g4;

        // batch the 4 K b128 reads up front
        bf16x8 ka[2][2];
#pragma unroll
        for (int ntl = 0; ntl < 2; ++ntl) {
            ka[ntl][0] = *(const bf16x8*)(KB + koffs[ntl][0]);
            ka[ntl][1] = *(const bf16x8*)(KB + koffs[ntl][1]);
        }

        // ---- S^T = K.Q^T; exp2 + mask -> merged P frags; 4 independent qs chains
        bf16x8 pa8[4];
#pragma unroll
        for (int ntl = 0; ntl < 2; ++ntl) {
            f32x4 c[4];
            __builtin_amdgcn_s_setprio(1);
#pragma unroll
            for (int qs = 0; qs < 4; ++qs) {
                c[qs] = mfma32(ka[ntl][0], qf[qs][0], z4);
                c[qs] = mfma32(ka[ntl][1], qf[qs][1], c[qs]);
            }
            __builtin_amdgcn_s_setprio(0);
#pragma unroll
            for (int qs = 0; qs < 4; ++qs) {
#pragma unroll
                for (int r = 0; r < 4; ++r) {
                    const float e = fast_exp2(c[qs][r]);
                    const int keep = sext_bit(nbs[qs], ntl * 16 + r);
                    const float p = __builtin_bit_cast(float,
                        __builtin_bit_cast(unsigned, e) & (unsigned)keep);
                    pa8[qs][ntl * 4 + r] = (__bf16)p;
                }
            }
        }

        // ---- row-sum + PV: V frags shared across all 4 qs (the per-q LDS halving)
        bf16x8 vv[4];
#pragma unroll
        for (int mt = 0; mt < 4; ++mt) vv[mt] = *(const bf16x8*)(VB + voffs[mt]);
        __builtin_amdgcn_s_setprio(1);
#pragma unroll
        for (int qs = 0; qs < 4; ++qs) osum[qs] = mfma32(pa8[qs], ones8, osum[qs]);
#pragma unroll
        for (int mt = 0; mt < 4; ++mt)
#pragma unroll
            for (int qs = 0; qs < 4; ++qs)
                o[qs][mt] = mfma32(pa8[qs], vv[mt], o[qs][mt]);
        __builtin_amdgcn_s_setprio(0);
    };

    auto window = [&](const char* X, const char* Y, int t, char* SX, char* SY) {
        if (t + 6 < NT_TILES) { stage(t + 6, SX); stage(t + 7, SY); }
        const unsigned* p0 = nb_base + (size_t)t * 4096;
        const unsigned* p1 = p0 + 4096;
        unsigned nw0[4], nw1[4];
#pragma unroll
        for (int qs = 0; qs < 4; ++qs) { nw0[qs] = p0[qs * 16 + ln]; nw1[qs] = p1[qs * 16 + ln]; }
        compute_tile(X, nw0);
        compute_tile(Y, nw1);
        __syncthreads();
    };

    // prologue: tiles 0..5 -> b0..b5
    stage(0, b0); stage(1, b1); stage(2, b2);
    stage(3, b3); stage(4, b4); stage(5, b5);
    __syncthreads();

#pragma unroll 1
    for (int i = 0; i < 4; ++i) {
        const int t = 8 * i;
        window(b0, b1, t,     b6, b7);
        window(b2, b3, t + 2, b0, b1);
        window(b4, b5, t + 4, b2, b3);
        window(b6, b7, t + 6, b4, b5);
    }

    // ---- epilogue: two 128-row passes; kh halves combined through LDS (ring is dead)
#pragma unroll
    for (int pass = 0; pass < 2; ++pass) {
        if ((qp >> 1) == pass) {
            const int qpl = qp & 1;
#pragma unroll
            for (int qs = 0; qs < 4; ++qs) {
#pragma unroll
                for (int mt = 0; mt < 4; ++mt)
#pragma unroll
                    for (int r = 0; r < 4; ++r)
                        Ep[(size_t)kh * 8192 + (qpl * 64 + qs * 16 + g * 4 + r) * 64 + mt * 16 + ln] = o[qs][mt][r];
                if (ln == 0) {
#pragma unroll
                    for (int r = 0; r < 4; ++r)
                        Os[kh * 128 + qpl * 64 + qs * 16 + g * 4 + r] = osum[qs][r];
                }
            }
        }
        __syncthreads();
        // cooperative, coalesced output: 128 rows x 64 d fp32 (512 threads -> 4 quads each)
#pragma unroll
        for (int p2 = 0; p2 < 4; ++p2) {
            const int idx = p2 * 512 + tid;
            const int row = idx >> 4, c4 = (idx & 15) * 4;
            const float sl = Os[row] + Os[128 + row];
            const float inv = (sl > 0.f) ? (1.f / sl) : 0.f;
            const float4 a  = *(const float4*)(Ep + row * 64 + c4);
            const float4 b4v = *(const float4*)(Ep + 8192 + row * 64 + c4);
            const float4 st = { (a.x + b4v.x) * inv, (a.y + b4v.y) * inv,
                                (a.z + b4v.z) * inv, (a.w + b4v.w) * inv };
            *(float4*)(out + ((size_t)bh * T_SEQ + qt * 256 + pass * 128 + row) * D_HEAD + c4) = st;
        }
        if (pass == 0) __syncthreads();   // Ep/Os reused by pass 1
    }
}

extern "C" void kernel_launch(void* const* d_in, const int* in_sizes, int n_in,
                              void* d_out, int out_size, void* d_ws, size_t ws_size,
                              hipStream_t stream) {
    const float* q    = (const float*)d_in[0];
    const float* k    = (const float*)d_in[1];
    const float* v    = (const float*)d_in[2];
    const int*   mask = (const int*)d_in[3];
    float*       out  = (float*)d_out;

    char* img = (char*)d_ws + WS_IMG;
    unsigned* nbt = (unsigned*)((char*)d_ws + WS_MB);

    prep_kv<<<dim3(NT_TILES, BH_N), 256, 0, stream>>>(k, v, img);
    mpack<<<(T_SEQ * T_SEQ) / 256, 256, 0, stream>>>(mask, nbt);
    attn18<<<dim3(QT_N * BH_N), 512, 0, stream>>>(q, img, nbt, out);
}